// Round 4
// baseline (164.404 us; speedup 1.0000x reference)
//
#include <hip/hip_runtime.h>

#define BATCH 16
#define CH    16
#define HH    128
#define WW    128
#define NC    8            // n_convs
#define TR    4            // output rows per block tile
#define HR    (TR + 2)     // 6 halo rows
#define FW    (WW + 2)     // 130 halo cols
#define NELEM (HR * FW)    // 780 staged elements per tile
#define NTHR  128
#define NSTG  ((NELEM + NTHR - 1) / NTHR)   // 7 staging slots per thread

// Per-element features: f0=silu(v), f1=tanh(v), f2=2t^2 (=T2+1), f3=T3=4t^3-3t.
// bias_j = sum_i (W0 - W2)[j,i] absorbs T0 and the +1 shift of f2, so features
// are exactly (0,0,0,0) at v=0 -> zero padding handled by feat(0)=0.
//
// Round-5 theory: R1/R3 showed ~80us kernel regardless of latency tweaks;
// per-CU arithmetic (HBM 24us, VALU 26us, LDS 21us; serial sum ~= measured)
// says the pipes run back-to-back because only 4 barrier-synced streams/CU
// exist and they phase-lock. This version: 128-thread blocks, ONE 4-row tile
// per block, single barrier -> 8 independent blocks resident/CU (2x streams)
// + 32-deep queue/CU for continuous re-stagger. Feat reads deduped 36->18
// per thread (6 distinct rows read once per dc into f[6], all 3 dr taps from
// registers). Register budget ~90 < 128 cap of (128,4) -> no spill.
__global__ __launch_bounds__(NTHR, 4)
void kan_conv_kernel(const float* __restrict__ x,
                     const float* __restrict__ cheby,   // (8,9,4)
                     const float* __restrict__ bwt,     // (8,9)
                     const float* __restrict__ scl,     // (8,9)
                     float* __restrict__ out)           // (16,128,128,128)
{
    __shared__ float4 feat[HR][FW];      // 12,480 B
    __shared__ float4 wgt[9 * NC];       // [tap*8 + j] = (bw, W1, W2, W3)
    __shared__ float  bias[NC];

    const int tid  = threadIdx.x;        // 0..127
    const int band = blockIdx.x * TR;    // 0,4,...,124
    const int bz   = blockIdx.y;         // plane = b*CH + c

    // ---- stage combined weights (tiny; L1/L2-resident after first blocks) ----
    if (tid < 9 * NC) {
        int j = tid / 9, i = tid % 9;
        float s = scl[j * 9 + i];
        wgt[i * NC + j] = make_float4(bwt[j * 9 + i],
                                      cheby[(j * 9 + i) * 4 + 1] * s,
                                      cheby[(j * 9 + i) * 4 + 2] * s,
                                      cheby[(j * 9 + i) * 4 + 3] * s);
    } else if (tid < 9 * NC + NC) {
        int j = tid - 9 * NC;
        float b = 0.f;
        #pragma unroll
        for (int i = 0; i < 9; ++i)
            b += (cheby[(j * 9 + i) * 4 + 0] - cheby[(j * 9 + i) * 4 + 2]) * scl[j * 9 + i];
        bias[j] = b;
    }

    // ---- stage halo tile: issue all loads back-to-back, then features ----
    const float* xp = x + (size_t)bz * HH * WW;
    float v[NSTG];
    #pragma unroll
    for (int k = 0; k < NSTG; ++k) {
        int idx = tid + NTHR * k;
        int row = idx / FW;              // magic-mul div
        int col = idx - row * FW;
        int gh  = band + row - 1;
        int gw  = col - 1;
        float nv = 0.f;
        if (idx < NELEM && (unsigned)gh < (unsigned)HH && (unsigned)gw < (unsigned)WW)
            nv = xp[gh * WW + gw];       // 4B/lane coalesced
        v[k] = nv;
    }
    #pragma unroll
    for (int k = 0; k < NSTG; ++k) {
        int idx = tid + NTHR * k;
        if (idx < NELEM) {
            int row = idx / FW;
            int col = idx - row * FW;
            float val = v[k];
            float e1 = __expf(val);
            float e2 = e1 * e1;                               // exp(2v)
            float sg = 1.f - __builtin_amdgcn_rcpf(1.f + e1); // sigmoid(v)
            float t  = 1.f - 2.f * __builtin_amdgcn_rcpf(e2 + 1.f); // tanh(v)
            float f2 = 2.f * t * t;                           // T2 + 1
            float f3 = 2.f * t * (f2 - 1.f) - t;              // T3
            feat[row][col] = make_float4(val * sg, t, f2, f3);
        }
    }
    __syncthreads();

    // ---- conv: thread owns col c, rows band..band+3 (consecutive) ----
    const int c = tid;                   // 0..127

    float acc[TR][NC];                   // 32 VGPRs
    #pragma unroll
    for (int s = 0; s < TR; ++s)
        #pragma unroll
        for (int j = 0; j < NC; ++j)
            acc[s][j] = bias[j];

    #pragma unroll
    for (int dc = 0; dc < 3; ++dc) {
        // read the 6 distinct feat rows for this dc ONCE (18 reads total)
        float4 f[HR];                    // 24 VGPRs
        #pragma unroll
        for (int rr = 0; rr < HR; ++rr)
            f[rr] = feat[rr][c + dc];    // 16B/lane: conflict-free b128
        #pragma unroll
        for (int dr = 0; dr < 3; ++dr) {
            #pragma unroll
            for (int j = 0; j < NC; ++j) {
                float4 w = wgt[(dr * 3 + dc) * NC + j];   // uniform LDS broadcast
                #pragma unroll
                for (int s = 0; s < TR; ++s) {
                    acc[s][j] += w.x * f[s + dr].x;
                    acc[s][j] += w.y * f[s + dr].y;
                    acc[s][j] += w.z * f[s + dr].z;
                    acc[s][j] += w.w * f[s + dr].w;
                }
            }
        }
    }

    // ---- store: each wave writes 64 consecutive floats (256B contiguous);
    //      no trailing barrier -> stores drain at endpgm under other blocks ----
    float* op = out + (size_t)(bz * NC) * HH * WW + (size_t)band * WW + c;
    #pragma unroll
    for (int j = 0; j < NC; ++j)
        #pragma unroll
        for (int s = 0; s < TR; ++s)
            op[(size_t)j * HH * WW + (size_t)s * WW] = acc[s][j];
}

extern "C" void kernel_launch(void* const* d_in, const int* in_sizes, int n_in,
                              void* d_out, int out_size, void* d_ws, size_t ws_size,
                              hipStream_t stream) {
    const float* x     = (const float*)d_in[0];
    const float* cheby = (const float*)d_in[1];
    const float* bwt   = (const float*)d_in[2];
    const float* scl   = (const float*)d_in[3];
    float* out = (float*)d_out;

    dim3 grid(HH / TR, BATCH * CH);      // 32 x 256 = 8192 blocks (32 deep/CU)
    dim3 block(NTHR);
    hipLaunchKernelGGL(kan_conv_kernel, grid, block, 0, stream, x, cheby, bwt, scl, out);
}

// Round 7
// 162.963 us; speedup vs baseline: 1.0088x; 1.0088x over previous
//
#include <hip/hip_runtime.h>

#define BATCH 16
#define CH    16
#define HH    128
#define WW    128
#define NC    8            // n_convs
#define TR    4            // output rows per block tile
#define HR    (TR + 2)     // 6 halo rows
#define FW    (WW + 2)     // 130 halo cols
#define NELEM (HR * FW)    // 780 staged elements per tile
#define NTHR  256
#define NSTG  4            // ceil(780/256)

// Per-element features: f0=silu(v), f1=tanh(v), f2=2t^2 (=T2+1), f3=T3=4t^3-3t.
// bias_j = sum_i (W0 - W2)[j,i] absorbs T0 and the +1 shift of f2, so features
// are exactly (0,0,0,0) at v=0 -> zero padding handled by feat(0)=0.
//
// Round-7 (resubmit after infra failure; R5's inline-asm s_load crash is
// reverted — plain HIP only). Occupancy theory finally under test:
// R0-R4 all ran ~90-110 VGPR = 4 waves/SIMD (25% occ); ~80us kernel ~=
// serial sum of HBM 24 + VALU 22 + LDS 21 us -> latency/phase exposure.
// This version fits under the 64-VGPR cliff: thread owns col c, ALL 4 rows,
// but only 4 of 8 convs (conv-split, not row-split: row-split would double
// the 72 broadcast weight reads and make LDS the bottleneck; conv-split
// keeps per-CU LDS cycles identical to R4). acc[4][4]=16 + f[6]=24 (scoped)
// + w4 + addr ~12 => ~56 VGPR peak.
// __launch_bounds__(256,8): 8 blocks/CU, LDS 8x12.5=100KB, 32 waves/CU (2x).
__global__ __launch_bounds__(NTHR, 8)
void kan_conv_kernel(const float* __restrict__ x,
                     const float* __restrict__ cheby,   // (8,9,4)
                     const float* __restrict__ bwt,     // (8,9)
                     const float* __restrict__ scl,     // (8,9)
                     float* __restrict__ out)           // (16,128,128,128)
{
    __shared__ float4 feat[HR][FW];      // 12,480 B
    __shared__ float4 wgt[9 * NC];       // [tap*8 + j] = (bw, W1, W2, W3)
    __shared__ float  bias[NC];

    const int tid  = threadIdx.x;        // 0..255
    const int band = blockIdx.x * TR;    // 0,4,...,124
    const int bz   = blockIdx.y;         // plane = b*CH + c

    // ---- stage combined weights (two different waves work in parallel) ----
    if (tid < 9 * NC) {
        int j = tid / 9, i = tid % 9;
        float s = scl[j * 9 + i];
        wgt[i * NC + j] = make_float4(bwt[j * 9 + i],
                                      cheby[(j * 9 + i) * 4 + 1] * s,
                                      cheby[(j * 9 + i) * 4 + 2] * s,
                                      cheby[(j * 9 + i) * 4 + 3] * s);
    } else if (tid >= 128 && tid < 128 + NC) {
        int j = tid - 128;
        float b = 0.f;
        #pragma unroll
        for (int i = 0; i < 9; ++i)
            b += (cheby[(j * 9 + i) * 4 + 0] - cheby[(j * 9 + i) * 4 + 2]) * scl[j * 9 + i];
        bias[j] = b;
    }

    // ---- stage halo tile: all loads issued back-to-back, then features ----
    const float* xp = x + (size_t)bz * HH * WW;
    float v[NSTG];
    #pragma unroll
    for (int k = 0; k < NSTG; ++k) {
        int idx = tid + NTHR * k;
        int row = idx / FW;              // magic-mul div
        int col = idx - row * FW;
        int gh  = band + row - 1;
        int gw  = col - 1;
        float nv = 0.f;
        if (idx < NELEM && (unsigned)gh < (unsigned)HH && (unsigned)gw < (unsigned)WW)
            nv = xp[gh * WW + gw];       // 4B/lane coalesced
        v[k] = nv;
    }
    #pragma unroll
    for (int k = 0; k < NSTG; ++k) {
        int idx = tid + NTHR * k;
        if (idx < NELEM) {
            int row = idx / FW;
            int col = idx - row * FW;
            float val = v[k];
            float e1 = __expf(val);
            float e2 = e1 * e1;                               // exp(2v)
            float sg = 1.f - __builtin_amdgcn_rcpf(1.f + e1); // sigmoid(v)
            float t  = 1.f - 2.f * __builtin_amdgcn_rcpf(e2 + 1.f); // tanh(v)
            float f2 = 2.f * t * t;                           // T2 + 1
            float f3 = 2.f * t * (f2 - 1.f) - t;              // T3
            feat[row][col] = make_float4(val * sg, t, f2, f3);
        }
    }
    __syncthreads();

    // ---- conv: thread owns col c, rows band..band+3, convs j0..j0+3 ----
    const int c  = tid & 127;            // 0..127
    const int j0 = (tid >> 7) * 4;       // 0 or 4

    float acc[TR][4];                    // 16 VGPRs
    #pragma unroll
    for (int s = 0; s < TR; ++s)
        #pragma unroll
        for (int j = 0; j < 4; ++j)
            acc[s][j] = bias[j0 + j];    // LDS broadcast

    #pragma unroll
    for (int dc = 0; dc < 3; ++dc) {
        // read the 6 distinct feat rows for this dc ONCE (18 reads total)
        float4 f[HR];                    // 24 VGPRs, live only in this scope
        #pragma unroll
        for (int rr = 0; rr < HR; ++rr)
            f[rr] = feat[rr][c + dc];    // 16B/lane: conflict-free b128
        #pragma unroll
        for (int dr = 0; dr < 3; ++dr) {
            #pragma unroll
            for (int j = 0; j < 4; ++j) {
                float4 w = wgt[(dr * 3 + dc) * NC + j0 + j];  // uniform broadcast
                #pragma unroll
                for (int s = 0; s < TR; ++s) {
                    acc[s][j] += w.x * f[s + dr].x;
                    acc[s][j] += w.y * f[s + dr].y;
                    acc[s][j] += w.z * f[s + dr].z;
                    acc[s][j] += w.w * f[s + dr].w;
                }
            }
        }
    }

    // ---- store: per (j,s) each wave writes 64 consecutive floats (256 B);
    //      no trailing barrier -> stores drain at endpgm under other blocks ----
    float* op = out + (size_t)(bz * NC + j0) * HH * WW + (size_t)band * WW + c;
    #pragma unroll
    for (int j = 0; j < 4; ++j)
        #pragma unroll
        for (int s = 0; s < TR; ++s)
            op[(size_t)j * HH * WW + (size_t)s * WW] = acc[s][j];
}

extern "C" void kernel_launch(void* const* d_in, const int* in_sizes, int n_in,
                              void* d_out, int out_size, void* d_ws, size_t ws_size,
                              hipStream_t stream) {
    const float* x     = (const float*)d_in[0];
    const float* cheby = (const float*)d_in[1];
    const float* bwt   = (const float*)d_in[2];
    const float* scl   = (const float*)d_in[3];
    float* out = (float*)d_out;

    dim3 grid(HH / TR, BATCH * CH);      // 32 x 256 = 8192 blocks
    dim3 block(NTHR);
    hipLaunchKernelGGL(kan_conv_kernel, grid, block, 0, stream, x, cheby, bwt, scl, out);
}